// Round 2
// baseline (13.391 us; speedup 1.0000x reference)
//
#include <hip/hip_runtime.h>
#include <math.h>

// L0-gated SINDy polynomial regression, eval-mode.
// out[b] = sum_j polyfeat(x_b)[j] * z[j] * w[j],
//   z = clip(sigmoid(qz)*1.2 - 0.1, 0, 1)
// x_b = [obs[b,0..2], act[b]]; 35 monomials of degree <= 3 over 4 vars,
// sklearn PolynomialFeatures ordering (bias, deg1, deg2 cwr, deg3 cwr).
//
// R2: 2 rows/thread (float2 loads, 8 B/lane) -> 8192 waves = 32 waves/CU
// (max occupancy) vs R1's 16/CU. Kernel is tiny (20 MB traffic); goal is
// faster ramp + latency tolerance.

#define NCOEF 35

__global__ __launch_bounds__(256) void l0sindy_kernel(
    const float* __restrict__ obs,   // [B,3]
    const float* __restrict__ act,   // [B,1]
    const float* __restrict__ w,     // [35,1]
    const float* __restrict__ qz,    // [35]
    float* __restrict__ out,         // [B,1]
    int npairs)                      // B/2
{
    __shared__ float c[NCOEF];
    const int tid = threadIdx.x;
    if (tid < NCOEF) {
        float q = qz[tid];
        float s = 1.0f / (1.0f + expf(-q));
        float z = fmaf(s, 1.2f, -0.1f);           // sigmoid*(zeta-gamma)+gamma
        z = fminf(fmaxf(z, 0.0f), 1.0f);
        c[tid] = z * w[tid];
    }
    __syncthreads();

    const int t = blockIdx.x * blockDim.x + tid;  // pair index: rows 2t, 2t+1
    if (t >= npairs) return;

    const float2* obs2 = reinterpret_cast<const float2*>(obs);
    const float2  o0 = obs2[3 * t + 0];           // x0_r0, x1_r0
    const float2  o1 = obs2[3 * t + 1];           // x2_r0, x0_r1
    const float2  o2 = obs2[3 * t + 2];           // x1_r1, x2_r1
    const float2  a  = reinterpret_cast<const float2*>(act)[t];

    const float xr[2][4] = {
        { o0.x, o0.y, o1.x, a.x },
        { o1.y, o2.x, o2.y, a.y },
    };

    float2 res;
    float* resp = reinterpret_cast<float*>(&res);

    #pragma unroll
    for (int r = 0; r < 2; ++r) {
        const float x0 = xr[r][0], x1 = xr[r][1], x2 = xr[r][2], x3 = xr[r][3];

        // degree-2 products (reused for degree 3)
        const float x00 = x0 * x0, x01 = x0 * x1, x02 = x0 * x2, x03 = x0 * x3;
        const float x11 = x1 * x1, x12 = x1 * x2, x13 = x1 * x3;
        const float x22 = x2 * x2, x23 = x2 * x3, x33 = x3 * x3;

        float acc = c[0];
        // degree 1
        acc = fmaf(c[1],  x0,  acc);
        acc = fmaf(c[2],  x1,  acc);
        acc = fmaf(c[3],  x2,  acc);
        acc = fmaf(c[4],  x3,  acc);
        // degree 2: (0,0)(0,1)(0,2)(0,3)(1,1)(1,2)(1,3)(2,2)(2,3)(3,3)
        acc = fmaf(c[5],  x00, acc);
        acc = fmaf(c[6],  x01, acc);
        acc = fmaf(c[7],  x02, acc);
        acc = fmaf(c[8],  x03, acc);
        acc = fmaf(c[9],  x11, acc);
        acc = fmaf(c[10], x12, acc);
        acc = fmaf(c[11], x13, acc);
        acc = fmaf(c[12], x22, acc);
        acc = fmaf(c[13], x23, acc);
        acc = fmaf(c[14], x33, acc);
        // degree 3: cwr over 4 vars
        acc = fmaf(c[15], x00 * x0, acc);  // (0,0,0)
        acc = fmaf(c[16], x00 * x1, acc);  // (0,0,1)
        acc = fmaf(c[17], x00 * x2, acc);  // (0,0,2)
        acc = fmaf(c[18], x00 * x3, acc);  // (0,0,3)
        acc = fmaf(c[19], x01 * x1, acc);  // (0,1,1)
        acc = fmaf(c[20], x01 * x2, acc);  // (0,1,2)
        acc = fmaf(c[21], x01 * x3, acc);  // (0,1,3)
        acc = fmaf(c[22], x02 * x2, acc);  // (0,2,2)
        acc = fmaf(c[23], x02 * x3, acc);  // (0,2,3)
        acc = fmaf(c[24], x03 * x3, acc);  // (0,3,3)
        acc = fmaf(c[25], x11 * x1, acc);  // (1,1,1)
        acc = fmaf(c[26], x11 * x2, acc);  // (1,1,2)
        acc = fmaf(c[27], x11 * x3, acc);  // (1,1,3)
        acc = fmaf(c[28], x12 * x2, acc);  // (1,2,2)
        acc = fmaf(c[29], x12 * x3, acc);  // (1,2,3)
        acc = fmaf(c[30], x13 * x3, acc);  // (1,3,3)
        acc = fmaf(c[31], x22 * x2, acc);  // (2,2,2)
        acc = fmaf(c[32], x22 * x3, acc);  // (2,2,3)
        acc = fmaf(c[33], x23 * x3, acc);  // (2,3,3)
        acc = fmaf(c[34], x33 * x3, acc);  // (3,3,3)

        resp[r] = acc;
    }

    reinterpret_cast<float2*>(out)[t] = res;
}

extern "C" void kernel_launch(void* const* d_in, const int* in_sizes, int n_in,
                              void* d_out, int out_size, void* d_ws, size_t ws_size,
                              hipStream_t stream) {
    const float* obs = (const float*)d_in[0];   // [B,3]
    const float* act = (const float*)d_in[1];   // [B,1]
    const float* w   = (const float*)d_in[2];   // [35,1]
    const float* qz  = (const float*)d_in[3];   // [35]
    float* out = (float*)d_out;

    const int B = in_sizes[0] / 3;              // 1048576
    const int npairs = B / 2;                   // 524288
    const int block = 256;
    const int grid = (npairs + block - 1) / block;  // 2048

    l0sindy_kernel<<<grid, block, 0, stream>>>(obs, act, w, qz, out, npairs);
}

// Round 3
// 10.106 us; speedup vs baseline: 1.3251x; 1.3251x over previous
//
#include <hip/hip_runtime.h>
#include <math.h>

// L0-gated SINDy polynomial regression, eval-mode.
// out[b] = sum_j polyfeat(x_b)[j] * z[j] * w[j],
//   z = clip(sigmoid(qz)*1.2 - 0.1, 0, 1)
// x_b = [obs[b,0..2], act[b]]; 35 monomials of degree <= 3 over 4 vars,
// sklearn PolynomialFeatures ordering (bias, deg1, deg2 cwr, deg3 cwr).
//
// R3: 8 rows/thread, all float4 loads (6x obs4 + 2x act4 in flight per
// thread) -> latency hiding via ILP; grid 512 wg (fast dispatch ramp).
// R2 showed narrower loads + more waves regress; this goes the other way.

#define NCOEF 35

__global__ __launch_bounds__(256) void l0sindy_kernel(
    const float* __restrict__ obs,   // [B,3]
    const float* __restrict__ act,   // [B,1]
    const float* __restrict__ w,     // [35,1]
    const float* __restrict__ qz,    // [35]
    float* __restrict__ out,         // [B,1]
    int noct)                        // B/8
{
    __shared__ float c[NCOEF];
    const int tid = threadIdx.x;
    if (tid < NCOEF) {
        float q = qz[tid];
        float s = 1.0f / (1.0f + expf(-q));
        float z = fmaf(s, 1.2f, -0.1f);           // sigmoid*(zeta-gamma)+gamma
        z = fminf(fmaxf(z, 0.0f), 1.0f);
        c[tid] = z * w[tid];
    }
    __syncthreads();

    const int t = blockIdx.x * blockDim.x + tid;  // octet index: rows 8t..8t+7
    if (t >= noct) return;

    const float4* obs4 = reinterpret_cast<const float4*>(obs);
    const float4* act4 = reinterpret_cast<const float4*>(act);

    const float4 o0 = obs4[6 * t + 0];
    const float4 o1 = obs4[6 * t + 1];
    const float4 o2 = obs4[6 * t + 2];
    const float4 o3 = obs4[6 * t + 3];
    const float4 o4 = obs4[6 * t + 4];
    const float4 o5 = obs4[6 * t + 5];
    const float4 a0 = act4[2 * t + 0];
    const float4 a1 = act4[2 * t + 1];

    // de-interleave 8 rows of [x0,x1,x2] + act
    const float xr[8][4] = {
        { o0.x, o0.y, o0.z, a0.x },
        { o0.w, o1.x, o1.y, a0.y },
        { o1.z, o1.w, o2.x, a0.z },
        { o2.y, o2.z, o2.w, a0.w },
        { o3.x, o3.y, o3.z, a1.x },
        { o3.w, o4.x, o4.y, a1.y },
        { o4.z, o4.w, o5.x, a1.z },
        { o5.y, o5.z, o5.w, a1.w },
    };

    float res[8];

    #pragma unroll
    for (int r = 0; r < 8; ++r) {
        const float x0 = xr[r][0], x1 = xr[r][1], x2 = xr[r][2], x3 = xr[r][3];

        // degree-2 products (reused for degree 3)
        const float x00 = x0 * x0, x01 = x0 * x1, x02 = x0 * x2, x03 = x0 * x3;
        const float x11 = x1 * x1, x12 = x1 * x2, x13 = x1 * x3;
        const float x22 = x2 * x2, x23 = x2 * x3, x33 = x3 * x3;

        float acc = c[0];
        // degree 1
        acc = fmaf(c[1],  x0,  acc);
        acc = fmaf(c[2],  x1,  acc);
        acc = fmaf(c[3],  x2,  acc);
        acc = fmaf(c[4],  x3,  acc);
        // degree 2: (0,0)(0,1)(0,2)(0,3)(1,1)(1,2)(1,3)(2,2)(2,3)(3,3)
        acc = fmaf(c[5],  x00, acc);
        acc = fmaf(c[6],  x01, acc);
        acc = fmaf(c[7],  x02, acc);
        acc = fmaf(c[8],  x03, acc);
        acc = fmaf(c[9],  x11, acc);
        acc = fmaf(c[10], x12, acc);
        acc = fmaf(c[11], x13, acc);
        acc = fmaf(c[12], x22, acc);
        acc = fmaf(c[13], x23, acc);
        acc = fmaf(c[14], x33, acc);
        // degree 3: cwr over 4 vars
        acc = fmaf(c[15], x00 * x0, acc);  // (0,0,0)
        acc = fmaf(c[16], x00 * x1, acc);  // (0,0,1)
        acc = fmaf(c[17], x00 * x2, acc);  // (0,0,2)
        acc = fmaf(c[18], x00 * x3, acc);  // (0,0,3)
        acc = fmaf(c[19], x01 * x1, acc);  // (0,1,1)
        acc = fmaf(c[20], x01 * x2, acc);  // (0,1,2)
        acc = fmaf(c[21], x01 * x3, acc);  // (0,1,3)
        acc = fmaf(c[22], x02 * x2, acc);  // (0,2,2)
        acc = fmaf(c[23], x02 * x3, acc);  // (0,2,3)
        acc = fmaf(c[24], x03 * x3, acc);  // (0,3,3)
        acc = fmaf(c[25], x11 * x1, acc);  // (1,1,1)
        acc = fmaf(c[26], x11 * x2, acc);  // (1,1,2)
        acc = fmaf(c[27], x11 * x3, acc);  // (1,1,3)
        acc = fmaf(c[28], x12 * x2, acc);  // (1,2,2)
        acc = fmaf(c[29], x12 * x3, acc);  // (1,2,3)
        acc = fmaf(c[30], x13 * x3, acc);  // (1,3,3)
        acc = fmaf(c[31], x22 * x2, acc);  // (2,2,2)
        acc = fmaf(c[32], x22 * x3, acc);  // (2,2,3)
        acc = fmaf(c[33], x23 * x3, acc);  // (2,3,3)
        acc = fmaf(c[34], x33 * x3, acc);  // (3,3,3)

        res[r] = acc;
    }

    float4* out4 = reinterpret_cast<float4*>(out);
    out4[2 * t + 0] = make_float4(res[0], res[1], res[2], res[3]);
    out4[2 * t + 1] = make_float4(res[4], res[5], res[6], res[7]);
}

extern "C" void kernel_launch(void* const* d_in, const int* in_sizes, int n_in,
                              void* d_out, int out_size, void* d_ws, size_t ws_size,
                              hipStream_t stream) {
    const float* obs = (const float*)d_in[0];   // [B,3]
    const float* act = (const float*)d_in[1];   // [B,1]
    const float* w   = (const float*)d_in[2];   // [35,1]
    const float* qz  = (const float*)d_in[3];   // [35]
    float* out = (float*)d_out;

    const int B = in_sizes[0] / 3;              // 1048576
    const int noct = B / 8;                     // 131072
    const int block = 256;
    const int grid = (noct + block - 1) / block;  // 512

    l0sindy_kernel<<<grid, block, 0, stream>>>(obs, act, w, qz, out, noct);
}